// Round 6
// baseline (936.727 us; speedup 1.0000x reference)
//
#include <hip/hip_runtime.h>
#include <hip/hip_bf16.h>

// Problem constants
#define BATCH 16
#define CDIM  256   // embedding dim / K of the GEMM
#define HDIM  64
#define WDIM  64
#define NQ    65536   // BATCH*HDIM*WDIM
#define NE    1024    // codebook size
#define BM2   64      // queries per block (one full w-row)
#define KB2   16      // k-chunk per B tile
#define BROW  516     // Bs row stride: 512 + 4 pad -> 2-way (free) write conflicts

// d_out layout (floats): [0]=loss, [1..16777216]=z_q_st, [16777217..16842752]=idx, [16842753]=perplexity
#define ZQ_OFF   1
#define IDX_OFF  16777217
#define PERP_OFF 16842753

// ws layout: ee float[1024] @0 ; hist int[1024] @4096 ; loss_part double[256] @8192
#define WS_EE_OFF    0
#define WS_HIST_OFF  4096
#define WS_LOSS_OFF  8192

// ---- numpy-pairwise sum-of-squares over 128 contiguous floats (8-accumulator tree) ----
__device__ __forceinline__ float pw128_sq(const float* __restrict__ p) {
    float r[8];
#pragma unroll
    for (int j = 0; j < 8; j++) r[j] = __fmul_rn(p[j], p[j]);
#pragma unroll
    for (int i = 8; i < 128; i += 8) {
#pragma unroll
        for (int j = 0; j < 8; j++) r[j] = __fadd_rn(r[j], __fmul_rn(p[i + j], p[i + j]));
    }
    return __fadd_rn(__fadd_rn(__fadd_rn(r[0], r[1]), __fadd_rn(r[2], r[3])),
                     __fadd_rn(__fadd_rn(r[4], r[5]), __fadd_rn(r[6], r[7])));
}

// ---- k1: codebook norms (numpy-pairwise), zero hist + loss accumulators ----
__global__ void vq_prep(const float* __restrict__ W, float* __restrict__ ee,
                        int* __restrict__ hist, double* __restrict__ loss_part) {
    int t = blockIdx.x * 256 + threadIdx.x;   // 0..1023, grid=4
    hist[t] = 0;
    if (t < 256) loss_part[t] = 0.0;
    const float* p = W + (size_t)t * CDIM;
    ee[t] = __fadd_rn(pw128_sq(p), pw128_sq(p + 128));
}

// ---- k2: fused distance GEMM + argmin ----
// 512 threads, 64 queries/block. Wave w handles q0=w*8 (8 q) x 1024 codes.
// Thread tile 8q x 8e. Bs double-buffered 512-code x 16-k tiles; A[k][q] resident.
//
// REGISTER BUDGET (rounds 3-5 lesson): the AMDGPU allocator defaults to a
// 4-waves/EU target (128 VGPR cap) regardless of __launch_bounds__'s second
// arg, and spilled acc[8][8] to scratch: 650 MB HBM writes, VALUBusy 33%.
// amdgpu_waves_per_eu(2,2) pins the budget to 512/2 = 256 VGPRs/wave, which
// matches the LDS-forced occupancy (133 KB -> 1 block/CU = 2 waves/EU).
__global__ __launch_bounds__(512)
__attribute__((amdgpu_waves_per_eu(2, 2)))
void vq_argmin(const float* __restrict__ z, const float* __restrict__ W,
               const float* __restrict__ ee, float* __restrict__ out_idx,
               int* __restrict__ hist) {
    __shared__ float A[CDIM][BM2];        // 64 KB, k-major
    __shared__ float Bs[2][KB2][BROW];    // 64.5 KB, k-major, double-buffered
    __shared__ float zz_s[BM2];
    __shared__ float tmp2[128];
    __shared__ float pD[BM2][8];
    __shared__ int   pI[BM2][8];
    // argmin reduction arrays alias A (A dead after main loop): 16 KB + 16 KB
    float (*redD)[64] = (float (*)[64])(&A[0][0]);
    int   (*redI)[64] = (int   (*)[64])(&A[64][0]);

    const int t  = threadIdx.x;          // 0..511
    const int n0 = blockIdx.x * BM2;
    const int b  = n0 >> 12;
    const int h  = (n0 >> 6) & 63;       // w0 == 0 (full w-row per block)

    // ---- stage A: A[c][w] = z[b, c, h, w]; 4096 float4, coalesced ----
    const float* zb = z + (size_t)b * (CDIM * HDIM * WDIM) + (size_t)h * WDIM;
#pragma unroll
    for (int v = 0; v < 8; v++) {
        int f  = v * 512 + t;            // 0..4095
        int c  = f >> 4;                 // 16 float4 per 64-wide row
        int w4 = f & 15;
        float4 val = *(const float4*)(zb + (size_t)c * (HDIM * WDIM) + w4 * 4);
        *(float4*)(&A[c][w4 * 4]) = val;
    }
    __syncthreads();

    // ---- zz per query, numpy-pairwise (two 128-blocks, 8 accumulators) ----
    if (t < 128) {
        int q = t >> 1, base = (t & 1) * 128;
        float r[8];
#pragma unroll
        for (int j = 0; j < 8; j++) { float x = A[base + j][q]; r[j] = __fmul_rn(x, x); }
        for (int i = 8; i < 128; i += 8) {
#pragma unroll
            for (int j = 0; j < 8; j++) { float x = A[base + i + j][q]; r[j] = __fadd_rn(r[j], __fmul_rn(x, x)); }
        }
        tmp2[t] = __fadd_rn(__fadd_rn(__fadd_rn(r[0], r[1]), __fadd_rn(r[2], r[3])),
                            __fadd_rn(__fadd_rn(r[4], r[5]), __fadd_rn(r[6], r[7])));
    }
    __syncthreads();
    if (t < BM2) zz_s[t] = __fadd_rn(tmp2[2 * t], tmp2[2 * t + 1]);

    const int tx = t & 63;
    const int ty = t >> 6;               // 0..7
    const int q0 = ty * 8;

    float bestD[8]; int bestI[8];
#pragma unroll
    for (int i = 0; i < 8; i++) { bestD[i] = 3.0e38f; bestI[i] = 0; }

    // Staging map for tile T (codes (T>>4)*512 .. +511, k (T&15)*16 .. +15):
    //   f = v*512 + t: e = f>>2 (4 float4 per 16-k row), kq = f&3.
    float4 breg[4];
#define LOAD_TILE(T_)                                                          \
    {                                                                          \
        int eb_ = ((T_) >> 4) * 512, kb_ = ((T_) & 15) * KB2;                  \
        _Pragma("unroll")                                                      \
        for (int v = 0; v < 4; v++) {                                          \
            int f = v * 512 + t;                                               \
            int e = f >> 2, kq = f & 3;                                        \
            breg[v] = *(const float4*)(W + (size_t)(eb_ + e) * CDIM + kb_ + kq * 4); \
        }                                                                      \
    }
#define WRITE_TILE(BUF_)                                                       \
    {                                                                          \
        _Pragma("unroll")                                                      \
        for (int v = 0; v < 4; v++) {                                          \
            int f = v * 512 + t;                                               \
            int e = f >> 2, kq = f & 3;                                        \
            Bs[BUF_][kq * 4 + 0][e] = breg[v].x;                               \
            Bs[BUF_][kq * 4 + 1][e] = breg[v].y;                               \
            Bs[BUF_][kq * 4 + 2][e] = breg[v].z;                               \
            Bs[BUF_][kq * 4 + 3][e] = breg[v].w;                               \
        }                                                                      \
    }

    float acc[8][8];
#pragma unroll
    for (int i = 0; i < 8; i++)
#pragma unroll
        for (int j = 0; j < 8; j++) acc[i][j] = 0.0f;

    // prolog: tile 0 -> Bs[0]; prefetch tile 1 into regs
    LOAD_TILE(0);
    WRITE_TILE(0);
    LOAD_TILE(1);
    __syncthreads();

    for (int T = 0; T < 32; T++) {
        const int buf = T & 1;
        if (T < 31) WRITE_TILE(1 - buf);     // safe: everyone synced after computing on 1-buf
        if (T < 30) LOAD_TILE(T + 2);

        const int kbg = (T & 15) * KB2;
#pragma unroll
        for (int k = 0; k < KB2; k++) {
            const float4 b0 = *(const float4*)(&Bs[buf][k][tx * 4]);
            const float4 b1 = *(const float4*)(&Bs[buf][k][256 + tx * 4]);
            const float4 a0 = *(const float4*)(&A[kbg + k][q0]);
            const float4 a1 = *(const float4*)(&A[kbg + k][q0 + 4]);
            float av[8] = {a0.x, a0.y, a0.z, a0.w, a1.x, a1.y, a1.z, a1.w};
            float bv[8] = {b0.x, b0.y, b0.z, b0.w, b1.x, b1.y, b1.z, b1.w};
#pragma unroll
            for (int i = 0; i < 8; i++)
#pragma unroll
                for (int j = 0; j < 8; j++)
                    acc[i][j] = __fmaf_rn(av[i], bv[j], acc[i][j]);
        }

        if ((T & 15) == 15) {
            // epilogue for eh = T>>4: d = fl(fl(zz+ee) - 2m); codes ascending -> strict <
            const int eb = (T >> 4) * 512;
            float4 eA = *(const float4*)(ee + eb + tx * 4);
            float4 eB = *(const float4*)(ee + eb + 256 + tx * 4);
            float ev[8] = {eA.x, eA.y, eA.z, eA.w, eB.x, eB.y, eB.z, eB.w};
#pragma unroll
            for (int i = 0; i < 8; i++) {
                float zzq = zz_s[q0 + i];
#pragma unroll
                for (int j = 0; j < 8; j++) {
                    float s = __fadd_rn(zzq, ev[j]);
                    float d = __fsub_rn(s, __fadd_rn(acc[i][j], acc[i][j]));
                    int   ix = eb + ((j < 4) ? (tx * 4 + j) : (256 + tx * 4 + (j - 4)));
                    if (d < bestD[i]) { bestD[i] = d; bestI[i] = ix; }
                    acc[i][j] = 0.0f;
                }
            }
        }
        __syncthreads();
    }

    // ---- cross-thread argmin reduce (lexicographic: min d, then min idx) ----
#pragma unroll
    for (int i = 0; i < 8; i++) { redD[q0 + i][tx] = bestD[i]; redI[q0 + i][tx] = bestI[i]; }
    __syncthreads();
    {
        int q = t >> 3, s = t & 7;       // 64 q x 8 segments
        float bd = redD[q][s * 8]; int bi = redI[q][s * 8];
#pragma unroll
        for (int u = 1; u < 8; u++) {
            float d2 = redD[q][s * 8 + u]; int i2 = redI[q][s * 8 + u];
            if (d2 < bd || (d2 == bd && i2 < bi)) { bd = d2; bi = i2; }
        }
        pD[q][s] = bd; pI[q][s] = bi;
    }
    __syncthreads();
    if (t < BM2) {
        float bd = pD[t][0]; int bi = pI[t][0];
#pragma unroll
        for (int u = 1; u < 8; u++) {
            float d2 = pD[t][u]; int i2 = pI[t][u];
            if (d2 < bd || (d2 == bd && i2 < bi)) { bd = d2; bi = i2; }
        }
        out_idx[n0 + t] = (float)bi;
        atomicAdd(&hist[bi], 1);
    }
}

// ---- k4: gather z_q, straight-through output, loss partials ----
__global__ void vq_gather(const float* __restrict__ z, const float* __restrict__ W,
                          const float* __restrict__ idxf, float* __restrict__ zq_out,
                          double* __restrict__ loss_part) {
    const int gid = blockIdx.x * 256 + threadIdx.x;  // grid=16384
    const int w4 = gid & 15;
    const int r  = gid >> 4;
    const int h  = r & 63;
    const int c  = (r >> 6) & 255;
    const int b  = r >> 14;
    const size_t off = (((size_t)(b * CDIM + c) * HDIM + h) * WDIM) + w4 * 4;
    const float4 zp = *(const float4*)(z + off);
    const int n = b * 4096 + h * 64 + w4 * 4;

    float zpv[4] = {zp.x, zp.y, zp.z, zp.w};
    float ov[4];
    double ls = 0.0;
#pragma unroll
    for (int l = 0; l < 4; l++) {
        int idx = (int)idxf[n + l];
        float zq = W[(size_t)idx * CDIM + c];
        float t1 = __fsub_rn(zq, zpv[l]);       // fl(z_q - zp)
        ov[l] = __fadd_rn(zpv[l], t1);          // fl(zp + fl(z_q - zp))
        ls += (double)t1 * (double)t1;
    }
    float4 o = {ov[0], ov[1], ov[2], ov[3]};
    *(float4*)(zq_out + off) = o;

#pragma unroll
    for (int s = 32; s > 0; s >>= 1) ls += __shfl_down(ls, s, 64);
    __shared__ double wsum[4];
    if ((threadIdx.x & 63) == 0) wsum[threadIdx.x >> 6] = ls;
    __syncthreads();
    if (threadIdx.x == 0) {
        double v = wsum[0] + wsum[1] + wsum[2] + wsum[3];
        atomicAdd(&loss_part[blockIdx.x & 255], v);
    }
}

// ---- k5: finalize loss + perplexity ----
__global__ void vq_final(const double* __restrict__ loss_part, const int* __restrict__ hist,
                         float* __restrict__ d_out) {
    __shared__ double s1[256], s2[256];
    const int t = threadIdx.x;
    double v = loss_part[t];
    double pv = 0.0;
#pragma unroll
    for (int j = 0; j < 4; j++) {
        int cnt = hist[t * 4 + j];
        double em = (double)cnt / 65536.0;
        pv += em * log(em + 1e-10);
    }
    s1[t] = v; s2[t] = pv;
    __syncthreads();
    for (int st = 128; st > 0; st >>= 1) {
        if (t < st) { s1[t] += s1[t + st]; s2[t] += s2[t + st]; }
        __syncthreads();
    }
    if (t == 0) {
        float m = (float)(s1[0] / 16777216.0);
        d_out[0] = 1.25f * m;                    // mean + 0.25*mean
        d_out[PERP_OFF] = (float)exp(-s2[0]);
    }
}

extern "C" void kernel_launch(void* const* d_in, const int* in_sizes, int n_in,
                              void* d_out, int out_size, void* d_ws, size_t ws_size,
                              hipStream_t stream) {
    const float* z = (const float*)d_in[0];
    const float* W = (const float*)d_in[1];
    float* out = (float*)d_out;

    float*  ee        = (float*)((char*)d_ws + WS_EE_OFF);
    int*    hist      = (int*)((char*)d_ws + WS_HIST_OFF);
    double* loss_part = (double*)((char*)d_ws + WS_LOSS_OFF);

    vq_prep<<<4, 256, 0, stream>>>(W, ee, hist, loss_part);
    vq_argmin<<<NQ / BM2, 512, 0, stream>>>(z, W, ee, out + IDX_OFF, hist);
    vq_gather<<<(NQ * CDIM / 4) / 256, 256, 0, stream>>>(z, W, out + IDX_OFF, out + ZQ_OFF, loss_part);
    vq_final<<<1, 256, 0, stream>>>(loss_part, hist, out);
}

// Round 7
// 806.930 us; speedup vs baseline: 1.1609x; 1.1609x over previous
//
#include <hip/hip_runtime.h>
#include <hip/hip_bf16.h>

// Problem constants
#define BATCH 16
#define CDIM  256   // embedding dim / K of the GEMM
#define HDIM  64
#define WDIM  64
#define NQ    65536   // BATCH*HDIM*WDIM
#define NE    1024    // codebook size
#define BM2   64      // queries per block (one full w-row)
#define KB2   16      // k-chunk per B tile
#define BROW  516     // Bs row stride: 512 + 4 pad -> 2-way (free) write conflicts

// d_out layout (floats): [0]=loss, [1..16777216]=z_q_st, [16777217..16842752]=idx, [16842753]=perplexity
#define ZQ_OFF   1
#define IDX_OFF  16777217
#define PERP_OFF 16842753

// ws layout: ee float[1024] @0 ; hist int[1024] @4096 ; loss_part double[256] @8192
#define WS_EE_OFF    0
#define WS_HIST_OFF  4096
#define WS_LOSS_OFF  8192

// ---- numpy-pairwise sum-of-squares over 128 contiguous floats (8-accumulator tree) ----
__device__ __forceinline__ float pw128_sq(const float* __restrict__ p) {
    float r[8];
#pragma unroll
    for (int j = 0; j < 8; j++) r[j] = __fmul_rn(p[j], p[j]);
#pragma unroll
    for (int i = 8; i < 128; i += 8) {
#pragma unroll
        for (int j = 0; j < 8; j++) r[j] = __fadd_rn(r[j], __fmul_rn(p[i + j], p[i + j]));
    }
    return __fadd_rn(__fadd_rn(__fadd_rn(r[0], r[1]), __fadd_rn(r[2], r[3])),
                     __fadd_rn(__fadd_rn(r[4], r[5]), __fadd_rn(r[6], r[7])));
}

// ---- k1: codebook norms (numpy-pairwise), zero hist + loss accumulators ----
__global__ void vq_prep(const float* __restrict__ W, float* __restrict__ ee,
                        int* __restrict__ hist, double* __restrict__ loss_part) {
    int t = blockIdx.x * 256 + threadIdx.x;   // 0..1023, grid=4
    hist[t] = 0;
    if (t < 256) loss_part[t] = 0.0;
    const float* p = W + (size_t)t * CDIM;
    ee[t] = __fadd_rn(pw128_sq(p), pw128_sq(p + 128));
}

// ---- k2: fused distance GEMM + argmin ----
// 512 threads, 64 queries/block. Wave ty handles q0=ty*8 (8 q) x 1024 codes.
// Thread tile 8q x 8e. Bs double-buffered 512-code x 16-k tiles; A[k][q] resident.
//
// REGISTER BUDGET (rounds 3-6 lesson): the allocator pins this kernel at 128
// VGPRs no matter what launch_bounds / amdgpu_waves_per_eu say. The round-3
// structure needed ~145 live regs -> breg spilled to scratch (650 MB HBM
// writes, VALUBusy 33%). Fix: no per-thread running argmin state. At each
// epilogue, butterfly-shuffle the wave's 64 lanes to a single (d,idx) per
// query and merge into LDS runD/runI (each wave owns its 8 queries
// exclusively). Peak live set ~110 regs.
__global__ __launch_bounds__(512)
__attribute__((amdgpu_waves_per_eu(2, 2)))
void vq_argmin(const float* __restrict__ z, const float* __restrict__ W,
               const float* __restrict__ ee, float* __restrict__ out_idx,
               int* __restrict__ hist) {
    __shared__ float A[CDIM][BM2];        // 64 KB, k-major
    __shared__ float Bs[2][KB2][BROW];    // 66 KB, k-major, double-buffered
    __shared__ float zz_s[BM2];
    __shared__ float tmp2[128];
    __shared__ float runD[BM2];           // running best distance per query
    __shared__ int   runI[BM2];           // running best index per query

    const int t  = threadIdx.x;          // 0..511
    const int n0 = blockIdx.x * BM2;
    const int b  = n0 >> 12;
    const int h  = (n0 >> 6) & 63;       // w0 == 0 (full w-row per block)

    // ---- stage A: A[c][w] = z[b, c, h, w]; 4096 float4, coalesced ----
    const float* zb = z + (size_t)b * (CDIM * HDIM * WDIM) + (size_t)h * WDIM;
#pragma unroll
    for (int v = 0; v < 8; v++) {
        int f  = v * 512 + t;            // 0..4095
        int c  = f >> 4;                 // 16 float4 per 64-wide row
        int w4 = f & 15;
        float4 val = *(const float4*)(zb + (size_t)c * (HDIM * WDIM) + w4 * 4);
        *(float4*)(&A[c][w4 * 4]) = val;
    }
    __syncthreads();

    // ---- zz per query, numpy-pairwise (two 128-blocks, 8 accumulators) ----
    if (t < 128) {
        int q = t >> 1, base = (t & 1) * 128;
        float r[8];
#pragma unroll
        for (int j = 0; j < 8; j++) { float x = A[base + j][q]; r[j] = __fmul_rn(x, x); }
        for (int i = 8; i < 128; i += 8) {
#pragma unroll
            for (int j = 0; j < 8; j++) { float x = A[base + i + j][q]; r[j] = __fadd_rn(r[j], __fmul_rn(x, x)); }
        }
        tmp2[t] = __fadd_rn(__fadd_rn(__fadd_rn(r[0], r[1]), __fadd_rn(r[2], r[3])),
                            __fadd_rn(__fadd_rn(r[4], r[5]), __fadd_rn(r[6], r[7])));
    }
    __syncthreads();
    if (t < BM2) {
        zz_s[t] = __fadd_rn(tmp2[2 * t], tmp2[2 * t + 1]);
        runD[t] = 3.0e38f;
        runI[t] = 0;
    }

    const int tx = t & 63;
    const int ty = t >> 6;               // 0..7
    const int q0 = ty * 8;

    // Staging map for tile T (codes (T>>4)*512 .. +511, k (T&15)*16 .. +15):
    //   f = v*512 + t: e = f>>2 (4 float4 per 16-k row), kq = f&3.
    float4 breg[4];
#define LOAD_TILE(T_)                                                          \
    {                                                                          \
        int eb_ = ((T_) >> 4) * 512, kb_ = ((T_) & 15) * KB2;                  \
        _Pragma("unroll")                                                      \
        for (int v = 0; v < 4; v++) {                                          \
            int f = v * 512 + t;                                               \
            int e = f >> 2, kq = f & 3;                                        \
            breg[v] = *(const float4*)(W + (size_t)(eb_ + e) * CDIM + kb_ + kq * 4); \
        }                                                                      \
    }
#define WRITE_TILE(BUF_)                                                       \
    {                                                                          \
        _Pragma("unroll")                                                      \
        for (int v = 0; v < 4; v++) {                                          \
            int f = v * 512 + t;                                               \
            int e = f >> 2, kq = f & 3;                                        \
            Bs[BUF_][kq * 4 + 0][e] = breg[v].x;                               \
            Bs[BUF_][kq * 4 + 1][e] = breg[v].y;                               \
            Bs[BUF_][kq * 4 + 2][e] = breg[v].z;                               \
            Bs[BUF_][kq * 4 + 3][e] = breg[v].w;                               \
        }                                                                      \
    }

    float acc[8][8];
#pragma unroll
    for (int i = 0; i < 8; i++)
#pragma unroll
        for (int j = 0; j < 8; j++) acc[i][j] = 0.0f;

    // prolog: tile 0 -> Bs[0]; prefetch tile 1 into regs
    LOAD_TILE(0);
    WRITE_TILE(0);
    LOAD_TILE(1);
    __syncthreads();                     // also publishes zz_s / runD / runI

    for (int T = 0; T < 32; T++) {
        const int buf = T & 1;
        if (T < 31) WRITE_TILE(1 - buf);     // safe: everyone synced after computing on 1-buf
        if (T < 30) LOAD_TILE(T + 2);

        const int kbg = (T & 15) * KB2;
#pragma unroll
        for (int k = 0; k < KB2; k++) {
            const float4 b0 = *(const float4*)(&Bs[buf][k][tx * 4]);
            const float4 b1 = *(const float4*)(&Bs[buf][k][256 + tx * 4]);
            const float4 a0 = *(const float4*)(&A[kbg + k][q0]);
            const float4 a1 = *(const float4*)(&A[kbg + k][q0 + 4]);
            float av[8] = {a0.x, a0.y, a0.z, a0.w, a1.x, a1.y, a1.z, a1.w};
            float bv[8] = {b0.x, b0.y, b0.z, b0.w, b1.x, b1.y, b1.z, b1.w};
#pragma unroll
            for (int i = 0; i < 8; i++)
#pragma unroll
                for (int j = 0; j < 8; j++)
                    acc[i][j] = __fmaf_rn(av[i], bv[j], acc[i][j]);
        }

        if ((T & 15) == 15) {
            // epilogue for eh = T>>4: d = fl(fl(zz+ee) - 2m).
            // Thread-local strict-< over ascending codes, then 64-lane
            // lexicographic-min butterfly, then merge into LDS running best.
            const int eb = (T >> 4) * 512;
            float4 eA = *(const float4*)(ee + eb + tx * 4);
            float4 eB = *(const float4*)(ee + eb + 256 + tx * 4);
            float ev[8] = {eA.x, eA.y, eA.z, eA.w, eB.x, eB.y, eB.z, eB.w};
#pragma unroll
            for (int i = 0; i < 8; i++) {
                float zzq = zz_s[q0 + i];
                float bd = 3.0e38f; int bi = 0;
#pragma unroll
                for (int j = 0; j < 8; j++) {
                    float s = __fadd_rn(zzq, ev[j]);
                    float d = __fsub_rn(s, __fadd_rn(acc[i][j], acc[i][j]));
                    int   ix = eb + ((j < 4) ? (tx * 4 + j) : (256 + tx * 4 + (j - 4)));
                    if (d < bd) { bd = d; bi = ix; }
                    acc[i][j] = 0.0f;
                }
#pragma unroll
                for (int off = 1; off < 64; off <<= 1) {
                    float d2 = __shfl_xor(bd, off, 64);
                    int   i2 = __shfl_xor(bi, off, 64);
                    if (d2 < bd || (d2 == bd && i2 < bi)) { bd = d2; bi = i2; }
                }
                if (tx == 0) {
                    float rd = runD[q0 + i]; int ri = runI[q0 + i];
                    if (bd < rd || (bd == rd && bi < ri)) {
                        runD[q0 + i] = bd; runI[q0 + i] = bi;
                    }
                }
            }
        }
        __syncthreads();
    }

    // ---- output: runD/runI already hold the global best per query ----
    if (t < BM2) {
        int bi = runI[t];
        out_idx[n0 + t] = (float)bi;
        atomicAdd(&hist[bi], 1);
    }
}

// ---- k4: gather z_q, straight-through output, loss partials ----
__global__ void vq_gather(const float* __restrict__ z, const float* __restrict__ W,
                          const float* __restrict__ idxf, float* __restrict__ zq_out,
                          double* __restrict__ loss_part) {
    const int gid = blockIdx.x * 256 + threadIdx.x;  // grid=16384
    const int w4 = gid & 15;
    const int r  = gid >> 4;
    const int h  = r & 63;
    const int c  = (r >> 6) & 255;
    const int b  = r >> 14;
    const size_t off = (((size_t)(b * CDIM + c) * HDIM + h) * WDIM) + w4 * 4;
    const float4 zp = *(const float4*)(z + off);
    const int n = b * 4096 + h * 64 + w4 * 4;

    float zpv[4] = {zp.x, zp.y, zp.z, zp.w};
    float ov[4];
    double ls = 0.0;
#pragma unroll
    for (int l = 0; l < 4; l++) {
        int idx = (int)idxf[n + l];
        float zq = W[(size_t)idx * CDIM + c];
        float t1 = __fsub_rn(zq, zpv[l]);       // fl(z_q - zp)
        ov[l] = __fadd_rn(zpv[l], t1);          // fl(zp + fl(z_q - zp))
        ls += (double)t1 * (double)t1;
    }
    float4 o = {ov[0], ov[1], ov[2], ov[3]};
    *(float4*)(zq_out + off) = o;

#pragma unroll
    for (int s = 32; s > 0; s >>= 1) ls += __shfl_down(ls, s, 64);
    __shared__ double wsum[4];
    if ((threadIdx.x & 63) == 0) wsum[threadIdx.x >> 6] = ls;
    __syncthreads();
    if (threadIdx.x == 0) {
        double v = wsum[0] + wsum[1] + wsum[2] + wsum[3];
        atomicAdd(&loss_part[blockIdx.x & 255], v);
    }
}

// ---- k5: finalize loss + perplexity ----
__global__ void vq_final(const double* __restrict__ loss_part, const int* __restrict__ hist,
                         float* __restrict__ d_out) {
    __shared__ double s1[256], s2[256];
    const int t = threadIdx.x;
    double v = loss_part[t];
    double pv = 0.0;
#pragma unroll
    for (int j = 0; j < 4; j++) {
        int cnt = hist[t * 4 + j];
        double em = (double)cnt / 65536.0;
        pv += em * log(em + 1e-10);
    }
    s1[t] = v; s2[t] = pv;
    __syncthreads();
    for (int st = 128; st > 0; st >>= 1) {
        if (t < st) { s1[t] += s1[t + st]; s2[t] += s2[t + st]; }
        __syncthreads();
    }
    if (t == 0) {
        float m = (float)(s1[0] / 16777216.0);
        d_out[0] = 1.25f * m;                    // mean + 0.25*mean
        d_out[PERP_OFF] = (float)exp(-s2[0]);
    }
}

extern "C" void kernel_launch(void* const* d_in, const int* in_sizes, int n_in,
                              void* d_out, int out_size, void* d_ws, size_t ws_size,
                              hipStream_t stream) {
    const float* z = (const float*)d_in[0];
    const float* W = (const float*)d_in[1];
    float* out = (float*)d_out;

    float*  ee        = (float*)((char*)d_ws + WS_EE_OFF);
    int*    hist      = (int*)((char*)d_ws + WS_HIST_OFF);
    double* loss_part = (double*)((char*)d_ws + WS_LOSS_OFF);

    vq_prep<<<4, 256, 0, stream>>>(W, ee, hist, loss_part);
    vq_argmin<<<NQ / BM2, 512, 0, stream>>>(z, W, ee, out + IDX_OFF, hist);
    vq_gather<<<(NQ * CDIM / 4) / 256, 256, 0, stream>>>(z, W, out + IDX_OFF, out + ZQ_OFF, loss_part);
    vq_final<<<1, 256, 0, stream>>>(loss_part, hist, out);
}